// Round 1
// baseline (315.741 us; speedup 1.0000x reference)
//
#include <hip/hip_runtime.h>

typedef _Float16 v8h __attribute__((ext_vector_type(8)));
typedef _Float16 v4h __attribute__((ext_vector_type(4)));
typedef float v4f __attribute__((ext_vector_type(4)));

// ---------------- async global->LDS, 16B per lane ----------------
__device__ __forceinline__ void gl16(const void* g, void* l) {
    __builtin_amdgcn_global_load_lds(
        (const __attribute__((address_space(1))) unsigned int*)g,
        (__attribute__((address_space(3))) unsigned int*)l, 16, 0, 0);
}

// ---------------- convert x (fp32 -> fp16), 8 elems/thread ----------------
__global__ __launch_bounds__(256) void k_cvt_x(const float* __restrict__ x,
                                               _Float16* __restrict__ x16) {
    int i = (blockIdx.x * 256 + threadIdx.x) * 8;
    float4 a = *(const float4*)(x + i);
    float4 b = *(const float4*)(x + i + 4);
    v8h h;
    h[0] = (_Float16)a.x; h[1] = (_Float16)a.y; h[2] = (_Float16)a.z; h[3] = (_Float16)a.w;
    h[4] = (_Float16)b.x; h[5] = (_Float16)b.y; h[6] = (_Float16)b.z; h[7] = (_Float16)b.w;
    *(v8h*)(x16 + i) = h;
}

// ------- convert + transpose W [1024][3072] fp32 -> Wt [3072][1024] fp16 -------
__global__ __launch_bounds__(256) void k_cvt_w(const float* __restrict__ W,
                                               _Float16* __restrict__ Wt) {
    __shared__ float T[64][68];
    int k0 = (blockIdx.x & 15) * 64;
    int n0 = (blockIdx.x >> 4) * 64;
    int t = threadIdx.x;
    int tr = t >> 4;   // 0..15
    int tc = t & 15;   // 0..15
#pragma unroll
    for (int rr = 0; rr < 4; rr++) {
        int kk = rr * 16 + tr;
        float4 v = *(const float4*)(W + (size_t)(k0 + kk) * 3072 + n0 + tc * 4);
        T[kk][tc * 4 + 0] = v.x; T[kk][tc * 4 + 1] = v.y;
        T[kk][tc * 4 + 2] = v.z; T[kk][tc * 4 + 3] = v.w;
    }
    __syncthreads();
#pragma unroll
    for (int ww = 0; ww < 4; ww++) {
        int nn = ww * 16 + tr;
        v4h h;
#pragma unroll
        for (int i = 0; i < 4; i++) h[i] = (_Float16)T[tc * 4 + i][nn];
        *(v4h*)(Wt + (size_t)(n0 + nn) * 1024 + k0 + tc * 4) = h;
    }
}

// ---------------- GEMM: C[16384][3072] = A(fp16) @ Bt(fp16)^T + bias ----------------
// 128x128 tile, BK=32, 4 waves (2x2), each wave 64x64 = 4x4 MFMA 16x16x32.
__global__ __launch_bounds__(256) void k_gemm(const _Float16* __restrict__ A,
                                              const _Float16* __restrict__ Bt,
                                              const float* __restrict__ bias,
                                              float* __restrict__ C) {
    __shared__ __align__(16) _Float16 As[128 * 32];  // [m][k] linear, no pad (global_load_lds)
    __shared__ __align__(16) _Float16 Bs[128 * 32];  // [n][k] linear
    int bm = blockIdx.x & 127;
    int bn = blockIdx.x >> 7;
    int m0 = bm * 128, n0 = bn * 128;
    int tid = threadIdx.x;
    int w = tid >> 6, lane = tid & 63;
    int quad = lane >> 4, l15 = lane & 15;
    int wm = (w & 1) * 64, wn = (w >> 1) * 64;

    // staging: 8 chunks of 1KiB per matrix; wave w stages chunks {w, w+4}
    int mc1 = w * 16 + (lane >> 2);
    int mc2 = (w + 4) * 16 + (lane >> 2);
    int k8 = (lane & 3) * 8;
    const _Float16* aS1 = A + (size_t)(m0 + mc1) * 1024 + k8;
    const _Float16* aS2 = A + (size_t)(m0 + mc2) * 1024 + k8;
    const _Float16* bS1 = Bt + (size_t)(n0 + mc1) * 1024 + k8;
    const _Float16* bS2 = Bt + (size_t)(n0 + mc2) * 1024 + k8;
    _Float16* lA1 = &As[w * 512];
    _Float16* lA2 = &As[(w + 4) * 512];
    _Float16* lB1 = &Bs[w * 512];
    _Float16* lB2 = &Bs[(w + 4) * 512];

    v4f acc[4][4] = {};

    for (int kt = 0; kt < 1024; kt += 32) {
        __syncthreads();               // previous tile's compute done
        gl16(aS1 + kt, lA1);
        gl16(aS2 + kt, lA2);
        gl16(bS1 + kt, lB1);
        gl16(bS2 + kt, lB2);
        __syncthreads();               // drains vmcnt(0): staged data visible
        v8h af[4], bf[4];
#pragma unroll
        for (int mi = 0; mi < 4; mi++)
            af[mi] = *(const v8h*)&As[(wm + mi * 16 + l15) * 32 + quad * 8];
#pragma unroll
        for (int ni = 0; ni < 4; ni++)
            bf[ni] = *(const v8h*)&Bs[(wn + ni * 16 + l15) * 32 + quad * 8];
#pragma unroll
        for (int mi = 0; mi < 4; mi++)
#pragma unroll
            for (int ni = 0; ni < 4; ni++)
                acc[mi][ni] = __builtin_amdgcn_mfma_f32_16x16x32_f16(af[mi], bf[ni], acc[mi][ni], 0, 0, 0);
    }

    // epilogue: D row = quad*4 + r (m), col = l15 (n); add bias
#pragma unroll
    for (int ni = 0; ni < 4; ni++) {
        int n = n0 + wn + ni * 16 + l15;
        float bv = bias[n];
#pragma unroll
        for (int mi = 0; mi < 4; mi++) {
            int mbase = m0 + wm + mi * 16 + quad * 4;
#pragma unroll
            for (int r = 0; r < 4; r++)
                C[(size_t)(mbase + r) * 3072 + n] = acc[mi][ni][r] + bv;
        }
    }
}

// ---------------- attention: one wave per position ----------------
// qkv row layout per pos: h in 0..15 : [q(64) | k(64) | v(64)]  (192 floats/head)
__global__ __launch_bounds__(256) void k_attn(const float* __restrict__ qkv,
                                              float* __restrict__ out) {
    __shared__ __align__(16) float lds[4 * 3408];  // per wave: 16*196 qkv + 16*17 P
    int tid = threadIdx.x;
    int w = tid >> 6, lane = tid & 63;
    int pos = blockIdx.x * 4 + w;
    float* L = &lds[w * 3408];
    float* P = L + 3136;
    const float* src = qkv + (size_t)pos * 3072;

    // stage 3072 floats -> padded LDS rows of 196 (Q @0, K @64, V @128)
#pragma unroll
    for (int ii = 0; ii < 12; ii++) {
        int e = (ii * 64 + lane) * 4;
        float4 v = *(const float4*)(src + e);
        int h = e / 192, r = e % 192;
        *(float4*)(L + h * 196 + r) = v;
    }
    __syncthreads();

    {   // S = QK^T - 20, banded exp, row-normalize; lane -> row h=lane&15, cols quad*4..+3
        int h = lane & 15, quad = lane >> 4;
        const float* Qr = L + h * 196;
        const float* Kr0 = L + (quad * 4 + 0) * 196 + 64;
        const float* Kr1 = L + (quad * 4 + 1) * 196 + 64;
        const float* Kr2 = L + (quad * 4 + 2) * 196 + 64;
        const float* Kr3 = L + (quad * 4 + 3) * 196 + 64;
        float a0 = 0.f, a1 = 0.f, a2 = 0.f, a3 = 0.f;
#pragma unroll
        for (int d4 = 0; d4 < 16; d4++) {
            float4 q = *(const float4*)(Qr + d4 * 4);
            float4 k0 = *(const float4*)(Kr0 + d4 * 4);
            float4 k1 = *(const float4*)(Kr1 + d4 * 4);
            float4 k2 = *(const float4*)(Kr2 + d4 * 4);
            float4 k3 = *(const float4*)(Kr3 + d4 * 4);
            a0 += q.x * k0.x + q.y * k0.y + q.z * k0.z + q.w * k0.w;
            a1 += q.x * k1.x + q.y * k1.y + q.z * k1.z + q.w * k1.w;
            a2 += q.x * k2.x + q.y * k2.y + q.z * k2.z + q.w * k2.w;
            a3 += q.x * k3.x + q.y * k3.y + q.z * k3.z + q.w * k3.w;
        }
        float s0 = a0 - 20.0f, s1 = a1 - 20.0f, s2 = a2 - 20.0f, s3 = a3 - 20.0f;
        float e0 = (s0 > 20.0f || s0 < -20.0f) ? 0.0f : expf(s0);
        float e1 = (s1 > 20.0f || s1 < -20.0f) ? 0.0f : expf(s1);
        float e2 = (s2 > 20.0f || s2 < -20.0f) ? 0.0f : expf(s2);
        float e3 = (s3 > 20.0f || s3 < -20.0f) ? 0.0f : expf(s3);
        float part = e0 + e1 + e2 + e3;
        part += __shfl_xor(part, 16, 64);
        part += __shfl_xor(part, 32, 64);
        float inv = 1.0f / part;
        P[h * 17 + quad * 4 + 0] = e0 * inv;
        P[h * 17 + quad * 4 + 1] = e1 * inv;
        P[h * 17 + quad * 4 + 2] = e2 * inv;
        P[h * 17 + quad * 4 + 3] = e3 * inv;
    }
    __syncthreads();

    {   // out[h][d] = sum_g P[h][g] * V[g][d]; lane -> h=lane>>2, d block = (lane&3)*16
        int h2 = lane >> 2, db = (lane & 3) * 16;
        float o[16];
#pragma unroll
        for (int i = 0; i < 16; i++) o[i] = 0.f;
#pragma unroll
        for (int g = 0; g < 16; g++) {
            float p = P[h2 * 17 + g];
            const float* Vr = L + g * 196 + 128 + db;
#pragma unroll
            for (int d4 = 0; d4 < 4; d4++) {
                float4 v = *(const float4*)(Vr + d4 * 4);
                o[d4 * 4 + 0] += p * v.x;
                o[d4 * 4 + 1] += p * v.y;
                o[d4 * 4 + 2] += p * v.z;
                o[d4 * 4 + 3] += p * v.w;
            }
        }
        float* dst = out + (size_t)pos * 1024 + h2 * 64 + db;
#pragma unroll
        for (int d4 = 0; d4 < 4; d4++) {
            float4 v;
            v.x = o[d4 * 4 + 0]; v.y = o[d4 * 4 + 1];
            v.z = o[d4 * 4 + 2]; v.w = o[d4 * 4 + 3];
            *(float4*)(dst + d4 * 4) = v;
        }
    }
}

extern "C" void kernel_launch(void* const* d_in, const int* in_sizes, int n_in,
                              void* d_out, int out_size, void* d_ws, size_t ws_size,
                              hipStream_t stream) {
    (void)in_sizes; (void)n_in; (void)out_size; (void)ws_size;
    const float* x    = (const float*)d_in[0];  // [4,4096,1024]
    const float* Wq   = (const float*)d_in[1];  // [1024,3072]
    const float* bq   = (const float*)d_in[2];  // [3072]
    float* out = (float*)d_out;                 // [4,4096,16,64] fp32

    char* ws = (char*)d_ws;
    _Float16* x16  = (_Float16*)ws;                          // 32 MiB
    _Float16* wt16 = (_Float16*)(ws + 33554432);             // 6 MiB
    float*    qkv  = (float*)(ws + 33554432 + 6291456);      // 192 MiB

    k_cvt_x<<<8192, 256, 0, stream>>>(x, x16);
    k_cvt_w<<<768, 256, 0, stream>>>(Wq, wt16);
    k_gemm<<<3072, 256, 0, stream>>>(x16, wt16, bq, qkv);
    k_attn<<<4096, 256, 0, stream>>>(qkv, out);
}

// Round 2
// 283.769 us; speedup vs baseline: 1.1127x; 1.1127x over previous
//
#include <hip/hip_runtime.h>

typedef _Float16 v8h __attribute__((ext_vector_type(8)));
typedef _Float16 v4h __attribute__((ext_vector_type(4)));
typedef _Float16 v2h __attribute__((ext_vector_type(2)));
typedef float v4f __attribute__((ext_vector_type(4)));

// ---------------- async global->LDS, 16B per lane ----------------
__device__ __forceinline__ void gl16(const void* g, void* l) {
    __builtin_amdgcn_global_load_lds(
        (const __attribute__((address_space(1))) unsigned int*)g,
        (__attribute__((address_space(3))) unsigned int*)l, 16, 0, 0);
}

// ---------------- convert x (fp32 -> fp16), 8 elems/thread ----------------
__global__ __launch_bounds__(256) void k_cvt_x(const float* __restrict__ x,
                                               _Float16* __restrict__ x16) {
    int i = (blockIdx.x * 256 + threadIdx.x) * 8;
    float4 a = *(const float4*)(x + i);
    float4 b = *(const float4*)(x + i + 4);
    v8h h;
    h[0] = (_Float16)a.x; h[1] = (_Float16)a.y; h[2] = (_Float16)a.z; h[3] = (_Float16)a.w;
    h[4] = (_Float16)b.x; h[5] = (_Float16)b.y; h[6] = (_Float16)b.z; h[7] = (_Float16)b.w;
    *(v8h*)(x16 + i) = h;
}

// ------- convert + transpose W [1024][3072] fp32 -> Wt [3072][1024] fp16 -------
__global__ __launch_bounds__(256) void k_cvt_w(const float* __restrict__ W,
                                               _Float16* __restrict__ Wt) {
    __shared__ float T[64][68];
    int k0 = (blockIdx.x & 15) * 64;
    int n0 = (blockIdx.x >> 4) * 64;
    int t = threadIdx.x;
    int tr = t >> 4;   // 0..15
    int tc = t & 15;   // 0..15
#pragma unroll
    for (int rr = 0; rr < 4; rr++) {
        int kk = rr * 16 + tr;
        float4 v = *(const float4*)(W + (size_t)(k0 + kk) * 3072 + n0 + tc * 4);
        T[kk][tc * 4 + 0] = v.x; T[kk][tc * 4 + 1] = v.y;
        T[kk][tc * 4 + 2] = v.z; T[kk][tc * 4 + 3] = v.w;
    }
    __syncthreads();
#pragma unroll
    for (int ww = 0; ww < 4; ww++) {
        int nn = ww * 16 + tr;
        v4h h;
#pragma unroll
        for (int i = 0; i < 4; i++) h[i] = (_Float16)T[tc * 4 + i][nn];
        *(v4h*)(Wt + (size_t)(n0 + nn) * 1024 + k0 + tc * 4) = h;
    }
}

// ---------------- GEMM: qkv16[16384][3072] = (A(fp16) @ Bt(fp16)^T + bias) as fp16 ----------------
// 128x128 tile, BK=32, 4 waves (2x2), each wave 64x64 = 4x4 MFMA 16x16x32.
__global__ __launch_bounds__(256) void k_gemm(const _Float16* __restrict__ A,
                                              const _Float16* __restrict__ Bt,
                                              const float* __restrict__ bias,
                                              _Float16* __restrict__ C) {
    __shared__ __align__(16) _Float16 As[128 * 32];  // [m][k] linear, no pad (global_load_lds)
    __shared__ __align__(16) _Float16 Bs[128 * 32];  // [n][k] linear
    int bm = blockIdx.x & 127;
    int bn = blockIdx.x >> 7;
    int m0 = bm * 128, n0 = bn * 128;
    int tid = threadIdx.x;
    int w = tid >> 6, lane = tid & 63;
    int quad = lane >> 4, l15 = lane & 15;
    int wm = (w & 1) * 64, wn = (w >> 1) * 64;

    // staging: 8 chunks of 1KiB per matrix; wave w stages chunks {w, w+4}
    int mc1 = w * 16 + (lane >> 2);
    int mc2 = (w + 4) * 16 + (lane >> 2);
    int k8 = (lane & 3) * 8;
    const _Float16* aS1 = A + (size_t)(m0 + mc1) * 1024 + k8;
    const _Float16* aS2 = A + (size_t)(m0 + mc2) * 1024 + k8;
    const _Float16* bS1 = Bt + (size_t)(n0 + mc1) * 1024 + k8;
    const _Float16* bS2 = Bt + (size_t)(n0 + mc2) * 1024 + k8;
    _Float16* lA1 = &As[w * 512];
    _Float16* lA2 = &As[(w + 4) * 512];
    _Float16* lB1 = &Bs[w * 512];
    _Float16* lB2 = &Bs[(w + 4) * 512];

    v4f acc[4][4] = {};

    for (int kt = 0; kt < 1024; kt += 32) {
        __syncthreads();               // previous tile's compute done
        gl16(aS1 + kt, lA1);
        gl16(aS2 + kt, lA2);
        gl16(bS1 + kt, lB1);
        gl16(bS2 + kt, lB2);
        __syncthreads();               // drains vmcnt(0): staged data visible
        v8h af[4], bf[4];
#pragma unroll
        for (int mi = 0; mi < 4; mi++)
            af[mi] = *(const v8h*)&As[(wm + mi * 16 + l15) * 32 + quad * 8];
#pragma unroll
        for (int ni = 0; ni < 4; ni++)
            bf[ni] = *(const v8h*)&Bs[(wn + ni * 16 + l15) * 32 + quad * 8];
#pragma unroll
        for (int mi = 0; mi < 4; mi++)
#pragma unroll
            for (int ni = 0; ni < 4; ni++)
                acc[mi][ni] = __builtin_amdgcn_mfma_f32_16x16x32_f16(af[mi], bf[ni], acc[mi][ni], 0, 0, 0);
    }

    // epilogue: D row = quad*4 + r (m), col = l15 (n); add bias, cast fp16
#pragma unroll
    for (int ni = 0; ni < 4; ni++) {
        int n = n0 + wn + ni * 16 + l15;
        float bv = bias[n];
#pragma unroll
        for (int mi = 0; mi < 4; mi++) {
            int mbase = m0 + wm + mi * 16 + quad * 4;
#pragma unroll
            for (int r = 0; r < 4; r++)
                C[(size_t)(mbase + r) * 3072 + n] = (_Float16)(acc[mi][ni][r] + bv);
        }
    }
}

// ---------------- attention: one wave per position, fp16 qkv in ----------------
// qkv row layout per pos: h in 0..15 : [q(64) | k(64) | v(64)]  (192 halves/head)
__global__ __launch_bounds__(256) void k_attn(const _Float16* __restrict__ qkv,
                                              float* __restrict__ out) {
    __shared__ __align__(16) _Float16 Lh[4][16 * 200];  // padded rows: 400 B stride
    __shared__ float Pb[4][16 * 17];
    int tid = threadIdx.x;
    int w = tid >> 6, lane = tid & 63;
    int pos = blockIdx.x * 4 + w;
    _Float16* L = Lh[w];
    float* P = Pb[w];
    const _Float16* src = qkv + (size_t)pos * 3072;

    // stage 3072 halves -> padded LDS rows of 200 (Q @0, K @64, V @128)
#pragma unroll
    for (int ii = 0; ii < 6; ii++) {
        int e = (ii * 64 + lane) * 8;
        v8h v = *(const v8h*)(src + e);
        int h = e / 192, r = e % 192;   // 8 | 192: chunk stays in one head row
        *(v8h*)(L + h * 200 + r) = v;
    }
    __syncthreads();

    {   // S = QK^T - 20, banded exp, row-normalize; lane: row h=lane&15, cols quad*4..+3
        int h = lane & 15, quad = lane >> 4;
        const _Float16* Qr = L + h * 200;
        v8h q[8];
#pragma unroll
        for (int d = 0; d < 8; d++) q[d] = *(const v8h*)(Qr + d * 8);
        float e4[4];
#pragma unroll
        for (int c = 0; c < 4; c++) {
            const _Float16* Kr = L + (quad * 4 + c) * 200 + 64;
            float a = 0.f;
#pragma unroll
            for (int d = 0; d < 8; d++) {
                v8h k = *(const v8h*)(Kr + d * 8);
#pragma unroll
                for (int j = 0; j < 4; j++)
                    a = __builtin_amdgcn_fdot2(((v2h*)&q[d])[j], ((v2h*)&k)[j], a, false);
            }
            float s = a - 20.0f;
            e4[c] = (s > 20.0f || s < -20.0f) ? 0.0f : __expf(s);
        }
        float part = e4[0] + e4[1] + e4[2] + e4[3];
        part += __shfl_xor(part, 16, 64);
        part += __shfl_xor(part, 32, 64);
        float inv = 1.0f / part;
#pragma unroll
        for (int c = 0; c < 4; c++) P[h * 17 + quad * 4 + c] = e4[c] * inv;
    }
    __syncthreads();

    {   // out[h][d] = sum_g P[h][g] * V[g][d]; lane: h=lane>>2, d block = (lane&3)*16
        int h2 = lane >> 2, db = (lane & 3) * 16;
        float o[16];
#pragma unroll
        for (int i = 0; i < 16; i++) o[i] = 0.f;
#pragma unroll
        for (int g = 0; g < 16; g++) {
            float p = P[h2 * 17 + g];
            const _Float16* Vr = L + g * 200 + 128 + db;
            v8h v0 = *(const v8h*)(Vr);
            v8h v1 = *(const v8h*)(Vr + 8);
#pragma unroll
            for (int i = 0; i < 8; i++) {
                o[i]     += p * (float)v0[i];
                o[8 + i] += p * (float)v1[i];
            }
        }
        float* dst = out + (size_t)pos * 1024 + h2 * 64 + db;
#pragma unroll
        for (int d4 = 0; d4 < 4; d4++) {
            float4 v;
            v.x = o[d4 * 4 + 0]; v.y = o[d4 * 4 + 1];
            v.z = o[d4 * 4 + 2]; v.w = o[d4 * 4 + 3];
            *(float4*)(dst + d4 * 4) = v;
        }
    }
}

extern "C" void kernel_launch(void* const* d_in, const int* in_sizes, int n_in,
                              void* d_out, int out_size, void* d_ws, size_t ws_size,
                              hipStream_t stream) {
    (void)in_sizes; (void)n_in; (void)out_size; (void)ws_size;
    const float* x  = (const float*)d_in[0];  // [4,4096,1024]
    const float* Wq = (const float*)d_in[1];  // [1024,3072]
    const float* bq = (const float*)d_in[2];  // [3072]
    float* out = (float*)d_out;               // [4,4096,16,64] fp32

    char* ws = (char*)d_ws;
    _Float16* x16   = (_Float16*)ws;                       // 32 MiB
    _Float16* wt16  = (_Float16*)(ws + (32u << 20));       // 6 MiB
    _Float16* qkv16 = (_Float16*)(ws + (38u << 20));       // 96 MiB

    k_cvt_x<<<8192, 256, 0, stream>>>(x, x16);
    k_cvt_w<<<768, 256, 0, stream>>>(Wq, wt16);
    k_gemm<<<3072, 256, 0, stream>>>(x16, wt16, bq, qkv16);
    k_attn<<<4096, 256, 0, stream>>>(qkv16, out);
}